// Round 2
// baseline (520.574 us; speedup 1.0000x reference)
//
#include <hip/hip_runtime.h>
#include <cstdint>

#define S_ 197
#define D_ 768
#define H_ 12
#define B_ 2
#define SS_ (S_*S_)
#define NBJ (B_*S_)      // 394

// ---- output offsets (floats), concat in reference return order ----
#define O_WN   0          // (B,H,S,S)  931416
#define O_SN   931416     // (B,S,S)    77618
#define O_RWN  1009034
#define O_PLNN 1086652
#define O_PLN  1164270    // (B,S,S,D)  59610624
#define O_AM   60774894   // (B,S) 394
#define O_ARM  60775288
#define O_ARLM 60775682

// ---- per-(b,j) precomputed stats layout (k index into gw[k*NBJ + bj]) ----
#define KG    0     // 78: G pairs (2x off-diag folded)   sn2 = sum p_k*G_k
#define KGW   78    // 78: w^2-weighted G pairs (2x off-diag)
#define KU    156   // 12: mean_d T_h  (pre-divided by 768)
#define KUW   168   // 12: sum_d w^2 T_h
#define KHD   180   // 12: sum_d hs*T_h
#define KHWD  192   // 12: sum_d w^2 hs T_h
#define KHSUM 204   // sum_d hs / 768
#define KHS2  205   // sum_d hs^2
#define KHW2S 206   // sum_d w^2 hs
#define KHW22 207   // sum_d w^2 hs^2
#define KTOT  208

// ---- workspace offsets (floats) ----
// WT is dead after kTransform; kAccS (runs later) reuses its region.
#define WS_ACC  0                    // 2*197*4*768 = 1210368
#define WS_WT   0                    // 589824 (aliases ACC; sequential stream makes this safe)
#define WS_T2   1210368              // 2*197*12*768 = 3631104
#define WS_TN   4841472              // 4728
#define WS_GW   4846200              // 208*394 = 81952
#define WS_IST  4928152              // 394
#define WS_SMU  4928546              // 394
#define WS_MUI  4928940              // 394
#define WS_DIAG 4929334              // 302592
// total 5231926 floats = 20.9 MB

__device__ __forceinline__ float wred64(float v) {
#pragma unroll
  for (int off = 32; off > 0; off >>= 1) v += __shfl_xor(v, off);
  return v;
}

// ---------------- W transpose: Wt[c][d] = W[d][c] (768x768) ----------------
__global__ __launch_bounds__(256) void kTranspose(const float* __restrict__ in,
                                                  float* __restrict__ outp) {
  __shared__ float tile[32][33];
  int x = blockIdx.x*32 + threadIdx.x;
  int y = blockIdx.y*32 + threadIdx.y;
#pragma unroll
  for (int k = 0; k < 32; k += 8) tile[threadIdx.y+k][threadIdx.x] = in[(y+k)*D_ + x];
  __syncthreads();
  x = blockIdx.y*32 + threadIdx.x;
  y = blockIdx.x*32 + threadIdx.y;
#pragma unroll
  for (int k = 0; k < 32; k += 8) outp[(y+k)*D_ + x] = tile[threadIdx.x][threadIdx.y+k];
}

// ------------- T2[b][s][h][d] = sum_v V[b,h,s,v]*W[d,h*64+v]; tnorm -------------
__global__ __launch_bounds__(256) void kTransform(const float* __restrict__ V,
                                                  const float* __restrict__ Wt,
                                                  float* __restrict__ T2,
                                                  float* __restrict__ tnorm) {
  int blk = blockIdx.x;             // 24*13
  int st = blk % 13; int bh = blk / 13;
  int h = bh % H_; int b = bh / H_;
  int s0 = st*16; int ns = min(16, S_ - s0);
  __shared__ float vt[16*64];
  __shared__ float red[4][16];
  int t = threadIdx.x;
  const float* Vbase = V + ((size_t)bh*S_ + s0)*64;
  for (int e = t; e < ns*64; e += 256) vt[e] = Vbase[e];
  __syncthreads();
  float acc2[16];
#pragma unroll
  for (int s = 0; s < 16; s++) acc2[s] = 0.f;
  for (int g = 0; g < 3; g++) {
    int d = t + g*256;
    float acc[16];
#pragma unroll
    for (int s = 0; s < 16; s++) acc[s] = 0.f;
    const float* wp = Wt + (size_t)h*64*D_ + d;
#pragma unroll 4
    for (int v = 0; v < 64; v++) {
      float wv = wp[(size_t)v*D_];
#pragma unroll
      for (int s = 0; s < 16; s++) acc[s] = fmaf(vt[s*64+v], wv, acc[s]);
    }
    for (int s = 0; s < ns; s++) {
      T2[((size_t)(b*S_ + s0+s)*H_ + h)*D_ + d] = acc[s];
      acc2[s] = fmaf(acc[s], acc[s], acc2[s]);
    }
  }
  int lane = t & 63, wq = t >> 6;
#pragma unroll
  for (int s = 0; s < 16; s++) {
    float v = wred64(acc2[s]);
    if (lane == 0) red[wq][s] = v;
  }
  __syncthreads();
  if (t < ns) {
    float v = red[0][t] + red[1][t] + red[2][t] + red[3][t];
    tnorm[bh*S_ + s0 + t] = sqrtf(v);
  }
}

// ------------- weighted_norm = |attn| * tnorm (elementwise) -------------
__global__ __launch_bounds__(256) void kWeightedNorm(const float* __restrict__ attn,
                                                     const float* __restrict__ tnorm,
                                                     float* __restrict__ outp) {
  int idx = blockIdx.x*256 + threadIdx.x;
  if (idx < B_*H_*SS_) {
    int bh = idx / SS_;
    int s = idx % S_;
    outp[O_WN + idx] = fabsf(attn[idx]) * tnorm[bh*S_ + s];
  }
}

// ------------- per-(b,j) Gram matrices + aux dots -------------
#define TP 772   // padded LDS row stride for T2 rows (float4-aligned, bank-spread)
__global__ __launch_bounds__(256) void kGram(const float* __restrict__ T2,
                                             const float* __restrict__ hs,
                                             const float* __restrict__ lnw,
                                             float* __restrict__ gw) {
  int bj = blockIdx.x;     // b*197 + j
  int t = threadIdx.x;
  __shared__ float tl[H_*TP];
  __shared__ float hl[D_];
  __shared__ float w2l[D_];
  const float* tb = T2 + (size_t)bj*H_*D_;
#pragma unroll
  for (int h = 0; h < H_; h++)
    for (int d = t; d < D_; d += 256) tl[h*TP + d] = tb[h*D_ + d];
  for (int d = t; d < D_; d += 256) {
    hl[d] = hs[(size_t)bj*D_ + d];
    float w = lnw[d];
    w2l[d] = w*w;
  }
  __syncthreads();
  float r = 0.f;
  if (t < 156) {
    int p = (t < 78) ? t : (t - 78);
    int h = 0; int pp = p;
    while (pp >= H_ - h) { pp -= H_ - h; h++; }
    int h2 = h + pp;
    const float4* ra = (const float4*)&tl[h*TP];
    const float4* rb = (const float4*)&tl[h2*TP];
    if (t < 78) {
      for (int q = 0; q < D_/4; q++) {
        float4 a = ra[q], b = rb[q];
        r = fmaf(a.x,b.x, fmaf(a.y,b.y, fmaf(a.z,b.z, fmaf(a.w,b.w, r))));
      }
    } else {
      const float4* rw = (const float4*)w2l;
      for (int q = 0; q < D_/4; q++) {
        float4 a = ra[q], b = rb[q], w = rw[q];
        r = fmaf(w.x*a.x,b.x, fmaf(w.y*a.y,b.y, fmaf(w.z*a.z,b.z, fmaf(w.w*a.w,b.w, r))));
      }
    }
    if (h != h2) r *= 2.f;
  } else if (t < 204) {
    int k = t - 156;        // 0..47
    int h = k % 12; int kind = k / 12;
    const float4* ra = (const float4*)&tl[h*TP];
    const float4* rw = (const float4*)w2l;
    const float4* rh = (const float4*)hl;
    for (int q = 0; q < D_/4; q++) {
      float4 a = ra[q];
      float4 m;
      if (kind == 0)      m = make_float4(1.f,1.f,1.f,1.f);
      else if (kind == 1) m = rw[q];
      else if (kind == 2) m = rh[q];
      else { float4 w = rw[q], hh = rh[q]; m = make_float4(w.x*hh.x, w.y*hh.y, w.z*hh.z, w.w*hh.w); }
      r = fmaf(m.x,a.x, fmaf(m.y,a.y, fmaf(m.z,a.z, fmaf(m.w,a.w, r))));
    }
    if (kind == 0) r *= (1.0f/768.0f);
  } else if (t < 208) {
    int kind = t - 204;
    const float4* rw = (const float4*)w2l;
    const float4* rh = (const float4*)hl;
    for (int q = 0; q < D_/4; q++) {
      float4 hh = rh[q]; float4 w = rw[q];
      float4 m;
      if (kind == 0)      m = make_float4(1.f,1.f,1.f,1.f);
      else if (kind == 1) m = hh;
      else if (kind == 2) m = w;
      else                m = make_float4(w.x*hh.x, w.y*hh.y, w.z*hh.z, w.w*hh.w);
      r = fmaf(m.x,hh.x, fmaf(m.y,hh.y, fmaf(m.z,hh.z, fmaf(m.w,hh.w, r))));
    }
    if (kind == 0) r *= (1.0f/768.0f);
  }
  if (t < KTOT) gw[(size_t)t*NBJ + bj] = r;   // t == k by construction
}

// ------------- norms via quadratic forms; per-thread, no cross-lane -------------
__global__ __launch_bounds__(256) void kNorms(const float* __restrict__ attn,
                                              const float* __restrict__ preln,
                                              const float* __restrict__ lnw,
                                              const float* __restrict__ gw,
                                              float* __restrict__ outp,
                                              float* __restrict__ wsIst,
                                              float* __restrict__ wsSmu,
                                              float* __restrict__ wsMui) {
  int bi = blockIdx.x;             // b*197+i
  int b = bi / S_; int i = bi % S_;
  int t = threadIdx.x;
  int lane = t & 63, wq = t >> 6;
  __shared__ float red[4][3];
  __shared__ float sc[2];          // istd, w2sum
  __shared__ float redmu[4];
  // phase A: istd from preln; w2sum
  float sx=0.f, sx2=0.f, sw2=0.f;
#pragma unroll
  for (int g = 0; g < 3; g++) {
    int d = t + g*256;
    float x = preln[(size_t)bi*D_ + d];
    sx += x; sx2 = fmaf(x,x,sx2);
    float w = lnw[d];
    sw2 = fmaf(w,w,sw2);
  }
  sx = wred64(sx); sx2 = wred64(sx2); sw2 = wred64(sw2);
  if (lane==0){ red[wq][0]=sx; red[wq][1]=sx2; red[wq][2]=sw2; }
  __syncthreads();
  if (t==0) {
    float a0=0,a1=0,a2=0;
#pragma unroll
    for (int k=0;k<4;k++){a0+=red[k][0];a1+=red[k][1];a2+=red[k][2];}
    float mu = a0*(1.f/768.f);
    float var = a1*(1.f/768.f) - mu*mu;
    float istd = rsqrtf(var + 1e-12f);
    sc[0]=istd; sc[1]=a2;
    wsIst[bi]=istd;
  }
  __syncthreads();
  float istd = sc[0], w2sum = sc[1];
  int j = t;
  float mu = 0.f;
  if (j < S_) {
    int bj = b*S_ + j;
    float a[12];
#pragma unroll
    for (int h=0; h<12; h++)
      a[h] = attn[(((size_t)(b*H_ + h))*S_ + i)*S_ + j];
    float sg=0.f, sgw=0.f;
    int k=0;
#pragma unroll
    for (int h=0; h<12; h++) {
#pragma unroll
      for (int h2=h; h2<12; h2++) {
        float pp = a[h]*a[h2];
        sg  = fmaf(pp, gw[(size_t)(KG+k)*NBJ + bj], sg);
        sgw = fmaf(pp, gw[(size_t)(KGW+k)*NBJ + bj], sgw);
        k++;
      }
    }
    float mus=0.f, s1w=0.f;
#pragma unroll
    for (int h=0; h<12; h++) {
      mus = fmaf(a[h], gw[(size_t)(KU+h)*NBJ + bj], mus);
      s1w = fmaf(a[h], gw[(size_t)(KUW+h)*NBJ + bj], s1w);
    }
    float rw2 = sg, s2w = sgw;
    mu = mus;
    if (j == i) {
      float hd=0.f, hwd=0.f;
#pragma unroll
      for (int h=0; h<12; h++) {
        hd  = fmaf(a[h], gw[(size_t)(KHD+h)*NBJ + bj], hd);
        hwd = fmaf(a[h], gw[(size_t)(KHWD+h)*NBJ + bj], hwd);
      }
      rw2 += 2.f*hd + gw[(size_t)KHS2*NBJ + bj];
      s2w += 2.f*hwd + gw[(size_t)KHW22*NBJ + bj];
      s1w += gw[(size_t)KHW2S*NBJ + bj];
      mu  += gw[(size_t)KHSUM*NBJ + bj];
      wsMui[bi] = mu;
    }
    float q = fmaf(mu*mu, w2sum, fmaf(-2.f*mu, s1w, s2w));
    int oIdx = bi*S_ + j;
    outp[O_SN  + oIdx] = sqrtf(fmaxf(sg,0.f));
    outp[O_RWN + oIdx] = sqrtf(fmaxf(rw2,0.f));
    outp[O_PLNN+ oIdx] = istd * sqrtf(fmaxf(q,0.f));
  }
  float m = wred64(mu);
  if (lane==0) redmu[wq]=m;
  __syncthreads();
  if (t==0) wsSmu[bi] = redmu[0]+redmu[1]+redmu[2]+redmu[3];
}

// ------------- post_ln (B,S,S,D): streaming, store-BW-bound -------------
__global__ __launch_bounds__(256) void kPostLN(const float* __restrict__ attn,
                                               const float* __restrict__ hs,
                                               const float* __restrict__ lnw,
                                               const float* __restrict__ T2,
                                               const float* __restrict__ gw,
                                               const float* __restrict__ wsIst,
                                               float* __restrict__ outp,
                                               float* __restrict__ wsDiag) {
  int blk = blockIdx.x;            // (b*197 + j)*2 + ihalf
  int ih = blk & 1; int bj = blk >> 1;
  int b = bj / S_; int j = bj % S_;
  int i0 = ih * 99;
  int ni = min(99, S_ - i0);
  int t = threadIdx.x;
  __shared__ float aL[99*12];
  __shared__ float uL[13];
  __shared__ float muL[99];
  __shared__ float istL[99];
  for (int e = t; e < ni*12; e += 256) {
    int ii = e / 12; int h = e % 12;
    aL[e] = attn[(((size_t)(b*H_+h))*S_ + (i0+ii))*S_ + j];
  }
  if (t < 12) uL[t] = gw[(size_t)(KU+t)*NBJ + bj];
  if (t == 12) uL[12] = gw[(size_t)KHSUM*NBJ + bj];
  if (t < ni) istL[t] = wsIst[b*S_ + i0 + t];
  // T2 row into registers (coalesced, read once per block)
  float t2r[12][3];
  const float* tb = T2 + (size_t)bj*H_*D_;
#pragma unroll
  for (int h=0; h<12; h++)
#pragma unroll
    for (int g=0; g<3; g++) t2r[h][g] = tb[h*D_ + t + g*256];
  float wv[3], hv[3];
#pragma unroll
  for (int g=0; g<3; g++) { wv[g] = lnw[t+g*256]; hv[g] = hs[(size_t)bj*D_ + t + g*256]; }
  __syncthreads();
  if (t < ni) {
    float m = 0.f;
#pragma unroll
    for (int h=0; h<12; h++) m = fmaf(aL[t*12+h], uL[h], m);
    if (i0 + t == j) m += uL[12];
    muL[t] = m;
  }
  __syncthreads();
  for (int ii = 0; ii < ni; ii++) {
    int iG = i0 + ii;
    const float4* ap = (const float4*)&aL[ii*12];
    float4 a0 = ap[0], a1 = ap[1], a2 = ap[2];
    float aa[12] = {a0.x,a0.y,a0.z,a0.w,a1.x,a1.y,a1.z,a1.w,a2.x,a2.y,a2.z,a2.w};
    float mu = muL[ii], ist = istL[ii];
    bool diag = (iG == j);
    float* po = outp + O_PLN + ((size_t)(b*S_+iG)*S_ + j)*D_;
#pragma unroll
    for (int g=0; g<3; g++) {
      float s = 0.f;
#pragma unroll
      for (int h=0; h<12; h++) s = fmaf(aa[h], t2r[h][g], s);
      float rw = s;
      if (diag) rw += hv[g];
      po[t + g*256] = (rw - mu) * ist * wv[g];
      if (diag) wsDiag[(size_t)bj*D_ + t + g*256] = s;
    }
  }
}

// ------------- accS[b,i,d] = sum_{j,h} a[h,i,j] T2[j,h,d] (split-K) -------------
#define AIT 8
#define ANC 4
#define AJW 50
__global__ __launch_bounds__(256) void kAccS(const float* __restrict__ attn,
                                             const float* __restrict__ T2,
                                             float* __restrict__ wsAcc) {
  int blk = blockIdx.x;   // ((b*25 + it)*4 + c)
  int c = blk & 3; int r = blk >> 2;
  int it = r % 25; int b = r / 25;
  int i0 = it * AIT;
  int j0 = c * AJW;
  int jw = min(AJW, S_ - j0);
  int t = threadIdx.x;
  __shared__ float aL[AJW*100];    // [jj][h*8+ii], row stride 100 (16B-aligned rows)
  for (int e = t; e < H_*AIT*jw; e += 256) {
    int h = e / (AIT*jw); int rem = e % (AIT*jw);
    int ii = rem / jw; int jj = rem % jw;
    int iG = i0 + ii;
    float v = 0.f;
    if (iG < S_) v = attn[(((size_t)(b*H_+h))*S_ + iG)*S_ + (j0+jj)];
    aL[jj*100 + h*8 + ii] = v;
  }
  __syncthreads();
  float acc[AIT][3];
#pragma unroll
  for (int ii=0; ii<AIT; ii++)
#pragma unroll
    for (int g=0; g<3; g++) acc[ii][g] = 0.f;
  for (int jj = 0; jj < jw; jj++) {
    const float* tb = T2 + ((size_t)(b*S_ + j0 + jj))*H_*D_;
#pragma unroll 2
    for (int h = 0; h < H_; h++) {
      float t2v[3];
#pragma unroll
      for (int g=0; g<3; g++) t2v[g] = tb[h*D_ + t + g*256];
      const float4* ap = (const float4*)&aL[jj*100 + h*8];
      float4 x = ap[0], y = ap[1];
      float av[8] = {x.x,x.y,x.z,x.w,y.x,y.y,y.z,y.w};
#pragma unroll
      for (int ii=0; ii<8; ii++)
#pragma unroll
        for (int g=0; g<3; g++) acc[ii][g] = fmaf(av[ii], t2v[g], acc[ii][g]);
    }
  }
#pragma unroll
  for (int ii=0; ii<AIT; ii++) {
    int iG = i0 + ii;
    if (iG < S_) {
#pragma unroll
      for (int g=0; g<3; g++)
        wsAcc[((size_t)(b*S_+iG)*ANC + c)*D_ + t + g*256] = acc[ii][g];
    }
  }
}

// ------------- mixing-ratio finalization -------------
__global__ __launch_bounds__(256) void kMixing(const float* __restrict__ wsAcc,
                                               const float* __restrict__ wsSmu,
                                               const float* __restrict__ wsDiag,
                                               const float* __restrict__ wsMui,
                                               const float* __restrict__ hs,
                                               const float* __restrict__ lnw,
                                               float* __restrict__ outp) {
  int bi = blockIdx.x;   // b*197 + i
  int t = threadIdx.x;
  float Smu = wsSmu[bi];
  float mui = wsMui[bi];
  float dmu = Smu - mui;
  float mS = 0.f, pS = 0.f, pRW = 0.f, mP = 0.f, pP = 0.f;
#pragma unroll
  for (int g = 0; g < 3; g++) {
    int d = t + g*256;
    float acc = 0.f;
#pragma unroll
    for (int cc = 0; cc < ANC; cc++) acc += wsAcc[((size_t)bi*ANC + cc)*D_ + d];
    float dg = wsDiag[(size_t)bi*D_ + d];
    float h = hs[(size_t)bi*D_ + d];
    float w = lnw[d];
    float mix = acc - dg;
    mS = fmaf(mix, mix, mS);
    pS = fmaf(dg, dg, pS);
    float drw = dg + h;
    pRW = fmaf(drw, drw, pRW);
    float mp = w * (mix - dmu);
    mP = fmaf(mp, mp, mP);
    float dp = w * (drw - mui);
    pP = fmaf(dp, dp, pP);
  }
  __shared__ float red[4][5];
  int lane = t & 63, wv = t >> 6;
  mS = wred64(mS); pS = wred64(pS); pRW = wred64(pRW); mP = wred64(mP); pP = wred64(pP);
  if (lane == 0) { red[wv][0]=mS; red[wv][1]=pS; red[wv][2]=pRW; red[wv][3]=mP; red[wv][4]=pP; }
  __syncthreads();
  if (t == 0) {
    float a0=0,a1=0,a2=0,a3=0,a4=0;
#pragma unroll
    for (int k = 0; k < 4; k++) { a0+=red[k][0]; a1+=red[k][1]; a2+=red[k][2]; a3+=red[k][3]; a4+=red[k][4]; }
    float mn = sqrtf(a0), pn = sqrtf(a1);
    outp[O_AM + bi] = mn / (mn + pn);
    float pnrw = sqrtf(a2);
    outp[O_ARM + bi] = mn / (mn + pnrw);
    float mnp = sqrtf(a3), pnp = sqrtf(a4);
    outp[O_ARLM + bi] = mnp / (mnp + pnp);
  }
}

extern "C" void kernel_launch(void* const* d_in, const int* in_sizes, int n_in,
                              void* d_out, int out_size, void* d_ws, size_t ws_size,
                              hipStream_t stream) {
  const float* hs    = (const float*)d_in[0];
  const float* attn  = (const float*)d_in[1];
  const float* V     = (const float*)d_in[2];
  const float* W     = (const float*)d_in[3];
  const float* lnw   = (const float*)d_in[4];
  const float* preln = (const float*)d_in[5];
  float* out = (float*)d_out;
  float* ws  = (float*)d_ws;

  kTranspose<<<dim3(24,24), dim3(32,8), 0, stream>>>(W, ws + WS_WT);
  kTransform<<<dim3(24*13), dim3(256), 0, stream>>>(V, ws + WS_WT, ws + WS_T2, ws + WS_TN);
  kWeightedNorm<<<dim3((B_*H_*SS_ + 255)/256), dim3(256), 0, stream>>>(attn, ws + WS_TN, out);
  kGram<<<dim3(NBJ), dim3(256), 0, stream>>>(ws + WS_T2, hs, lnw, ws + WS_GW);
  kNorms<<<dim3(NBJ), dim3(256), 0, stream>>>(attn, preln, lnw, ws + WS_GW, out,
                                              ws + WS_IST, ws + WS_SMU, ws + WS_MUI);
  kPostLN<<<dim3(NBJ*2), dim3(256), 0, stream>>>(attn, hs, lnw, ws + WS_T2, ws + WS_GW,
                                                 ws + WS_IST, out, ws + WS_DIAG);
  kAccS<<<dim3(200), dim3(256), 0, stream>>>(attn, ws + WS_T2, ws + WS_ACC);
  kMixing<<<dim3(NBJ), dim3(256), 0, stream>>>(ws + WS_ACC, ws + WS_SMU, ws + WS_DIAG, ws + WS_MUI,
                                               hs, lnw, out);
}